// Round 11
// baseline (173.019 us; speedup 1.0000x reference)
//
#include <hip/hip_runtime.h>

typedef float    f4 __attribute__((ext_vector_type(4)));
typedef _Float16 h8 __attribute__((ext_vector_type(8)));
typedef _Float16 h4 __attribute__((ext_vector_type(4)));
typedef _Float16 h2 __attribute__((ext_vector_type(2)));
typedef unsigned u4 __attribute__((ext_vector_type(4)));

#define DEV static __device__ __forceinline__

DEV f4 mfma16(h8 a, h8 b, f4 c) {
  return __builtin_amdgcn_mfma_f32_16x16x32_f16(a, b, c, 0, 0, 0);
}

DEV void gload16(const void* g, void* lds) {
  __builtin_amdgcn_global_load_lds((__attribute__((address_space(1))) void*)g,
                                   (__attribute__((address_space(3))) void*)lds,
                                   16, 0, 0);
}

DEV unsigned cvtpku(float a, float b) {
  return __builtin_bit_cast(unsigned, __builtin_amdgcn_cvt_pkrtz(a, b));
}

DEV float max3f(float a, float b, float c) {
  float d;
  asm("v_max3_f32 %0, %1, %2, %3" : "=v"(d) : "v"(a), "v"(b), "v"(c));
  return d;
}

// ---------------- fp32 -> fp16 conversion (x + packed weights) ----------------
__global__ __launch_bounds__(256) void cvt_all(
    const float* __restrict__ x,  const float* __restrict__ wq,
    const float* __restrict__ wk, const float* __restrict__ wv,
    const float* __restrict__ wo,
    _Float16* __restrict__ xb, _Float16* __restrict__ wqkv, _Float16* __restrict__ wob)
{
  int b = blockIdx.x;
  const float* src; _Float16* dst; int i4;
  if      (b < 8192)  { src = x;  dst = xb;                 i4 = b * 256; }
  else if (b < 9216)  { src = wq; dst = wqkv;               i4 = (b - 8192)  * 256; }
  else if (b < 10240) { src = wk; dst = wqkv + (1u << 20);  i4 = (b - 9216)  * 256; }
  else if (b < 11264) { src = wv; dst = wqkv + (2u << 20);  i4 = (b - 10240) * 256; }
  else                { src = wo; dst = wob;                i4 = (b - 11264) * 256; }
  i4 += threadIdx.x;
  f4 v = ((const f4*)src)[i4];
  h4 o;
  o[0] = (_Float16)v[0]; o[1] = (_Float16)v[1];
  o[2] = (_Float16)v[2]; o[3] = (_Float16)v[3];
  ((h4*)dst)[i4] = o;
}

// ======== 8-phase GEMM: C[M,N] = A[M,K] * Bt[N,K]^T, BN=256, BK=64 ==========
// 8 waves (2M x 4N); BM = MF*32 (MF = m-frags/wave = 8 or 4). Double-buffered
// quadrant regions; counted vmcnt (never 0 mid-loop); chunk^row&7 swizzle via
// pre-swizzled global source; setprio around each 16-MFMA cluster.
// MODE 0: fp32 C row-major. MODE 1: Q(scaled)/K [B,H,S,HD], V^T [B,H,HD,S].
template<int MODE, int MF>
__global__ __launch_bounds__(512) void gemmT(
    const _Float16* __restrict__ A, const _Float16* __restrict__ Bt,
    float* __restrict__ C,
    _Float16* __restrict__ Qo, _Float16* __restrict__ Ko, _Float16* __restrict__ Vo,
    int N, int Nt)
{
  constexpr int ASZ = MF * 16 * 64;   // A quadrant region (f16): 2 wm-panels
  constexpr int BSZ = 8192;           // B quadrant region: 4 wn-panels x 32 x 64
  constexpr int V1  = (MF == 8) ? 12 : 9;   // steady vmcnt @P1/P3/P5/P7
  constexpr int V2  = (MF == 8) ? 10 : 7;   // steady vmcnt @P2/P6
  constexpr int VL3 = (MF == 8) ? 8 : 6;    // last-iter drains
  constexpr int VL5 = (MF == 8) ? 4 : 3;
  constexpr int VL6 = (MF == 8) ? 2 : 1;
  __shared__ _Float16 Al[4 * ASZ];    // [buf][q]
  __shared__ _Float16 Bl[4 * BSZ];    // [buf][qn]

  int bid = blockIdx.x;
  int cpx = gridDim.x >> 3;                  // grid % 8 == 0 (bijective)
  bid = (bid & 7) * cpx + (bid >> 3);        // XCD-chunked swizzle
  int tm = bid / Nt, tn = bid - tm * Nt;
  int m0 = tm * (MF * 32), n0 = tn * 256;

  int t = threadIdx.x, w = t >> 6, l = t & 63, lo = l & 15, hi = l >> 4;
  int wm = w >> 2, wn = w & 3;

  // ---- staging sources (pre-swizzled chunk: involution chunk^=(row&7)) ----
  int rsc = t >> 3;                          // 0..63
  int csrc = ((t & 7) ^ (rsc & 7)) * 8;
  const _Float16 *As[2][2], *Bs[2][2];
  #pragma unroll
  for (int q = 0; q < 2; ++q) {
    if (MF == 8) {
      As[q][0] = A + (size_t)(m0 + q * 64 + rsc) * 1024 + csrc;
      As[q][1] = A + (size_t)(m0 + 128 + q * 64 + rsc) * 1024 + csrc;
    } else {
      As[q][0] = A + (size_t)(m0 + (t >> 8) * 64 + q * 32 + (rsc & 31)) * 1024 + csrc;
      As[q][1] = As[q][0];
    }
    #pragma unroll
    for (int h = 0; h < 2; ++h)
      Bs[q][h] = Bt + (size_t)(n0 + (2 * h + (t >> 8)) * 64 + q * 32 + (rsc & 31)) * 1024 + csrc;
  }
  _Float16* Adst = Al + w * 512;
  _Float16* Bdst = Bl + w * 512;

  // ---- fragment read offsets (f16 units) ----
  int awoff = wm * (MF * 8 * 64) + lo * 64;
  int bwoff = wn * 2048 + lo * 64;
  int s0 = (hi ^ (lo & 7)) * 8;
  int s1 = ((4 + hi) ^ (lo & 7)) * 8;

  f4 acc[MF][4] = {};
  h8 ar[MF / 2][2], br[2][2][2];

#define VMW(n)  asm volatile("s_waitcnt vmcnt(%0)" :: "n"(n) : "memory")
#define BARR    __builtin_amdgcn_s_barrier()
#define LGKM0   do { asm volatile("s_waitcnt lgkmcnt(0)" ::: "memory"); \
                     __builtin_amdgcn_sched_barrier(0); } while (0)
#define STA(BUF, Q, KO) do { \
    gload16(As[Q][0] + (KO), Adst + ((BUF) * 2 + (Q)) * ASZ); \
    if (MF == 8) gload16(As[Q][1] + (KO), Adst + ((BUF) * 2 + (Q)) * ASZ + 4096); \
  } while (0)
#define STB(BUF, QN, KO) do { \
    gload16(Bs[QN][0] + (KO), Bdst + ((BUF) * 2 + (QN)) * BSZ); \
    gload16(Bs[QN][1] + (KO), Bdst + ((BUF) * 2 + (QN)) * BSZ + 4096); \
  } while (0)
#define RDA(BUF, Q) do { \
    const _Float16* p_ = Al + ((BUF) * 2 + (Q)) * ASZ + awoff; \
    _Pragma("unroll") \
    for (int f_ = 0; f_ < MF / 2; ++f_) { \
      ar[f_][0] = *(const h8*)(p_ + f_ * 1024 + s0); \
      ar[f_][1] = *(const h8*)(p_ + f_ * 1024 + s1); } \
  } while (0)
#define RDB(BUF, QN, D) do { \
    const _Float16* p_ = Bl + ((BUF) * 2 + (QN)) * BSZ + bwoff; \
    br[D][0][0] = *(const h8*)(p_ + s0);        br[D][0][1] = *(const h8*)(p_ + s1); \
    br[D][1][0] = *(const h8*)(p_ + 1024 + s0); br[D][1][1] = *(const h8*)(p_ + 1024 + s1); \
  } while (0)
#define MM(MH, D) do { \
    __builtin_amdgcn_s_setprio(1); \
    _Pragma("unroll") \
    for (int f_ = 0; f_ < MF / 2; ++f_) \
      _Pragma("unroll") \
      for (int g_ = 0; g_ < 2; ++g_) { \
        acc[(MH) * (MF / 2) + f_][(D) * 2 + g_] = \
            mfma16(ar[f_][0], br[D][g_][0], acc[(MH) * (MF / 2) + f_][(D) * 2 + g_]); \
        acc[(MH) * (MF / 2) + f_][(D) * 2 + g_] = \
            mfma16(ar[f_][1], br[D][g_][1], acc[(MH) * (MF / 2) + f_][(D) * 2 + g_]); } \
    __builtin_amdgcn_s_setprio(0); \
    __builtin_amdgcn_sched_barrier(0); \
  } while (0)

  // prologue: tiles 0 (buf0) and 1 (buf1), region order Aq0,Bq0 | Bq1 | Aq1
  STA(0, 0, 0);  STB(0, 0, 0);  STB(0, 1, 0);  STA(0, 1, 0);
  STA(1, 0, 64); STB(1, 0, 64); STB(1, 1, 64); STA(1, 1, 64);

  int kof = 128;                         // element offset of tile 2it+2
  #pragma unroll 1
  for (int it = 0; it < 7; ++it) {       // NT/2 - 1 steady iterations
    VMW(V1); BARR; RDA(0, 0); RDB(0, 0, 0); LGKM0; MM(0, 0);
    VMW(V2); BARR; RDB(0, 1, 1); STA(0, 0, kof); STB(0, 0, kof); LGKM0; MM(0, 1);
    VMW(V1); BARR; RDA(0, 1); STB(0, 1, kof); LGKM0; MM(1, 1);
    BARR; STA(0, 1, kof); MM(1, 0);
    VMW(V1); BARR; RDA(1, 0); RDB(1, 0, 0); LGKM0; MM(0, 0);
    VMW(V2); BARR; RDB(1, 1, 1); STA(1, 0, kof + 64); STB(1, 0, kof + 64); LGKM0; MM(0, 1);
    VMW(V1); BARR; RDA(1, 1); STB(1, 1, kof + 64); LGKM0; MM(1, 1);
    BARR; STA(1, 1, kof + 64); MM(1, 0);
    kof += 128;
  }
  // last iteration: no staging, drain counts
  VMW(V1);  BARR; RDA(0, 0); RDB(0, 0, 0); LGKM0; MM(0, 0);
  VMW(V2);  BARR; RDB(0, 1, 1); LGKM0; MM(0, 1);
  VMW(VL3); BARR; RDA(0, 1); LGKM0; MM(1, 1);
  BARR; MM(1, 0);
  VMW(VL5); BARR; RDA(1, 0); RDB(1, 0, 0); LGKM0; MM(0, 0);
  VMW(VL6); BARR; RDB(1, 1, 1); LGKM0; MM(0, 1);
  VMW(0);   BARR; RDA(1, 1); LGKM0; MM(1, 1);
  BARR; MM(1, 0);

#undef VMW
#undef BARR
#undef LGKM0
#undef STA
#undef STB
#undef RDA
#undef RDB
#undef MM

  // ---- epilogue ----
  if (MODE == 0) {
    #pragma unroll
    for (int mi = 0; mi < MF; ++mi)
      #pragma unroll
      for (int nf = 0; nf < 4; ++nf)
        #pragma unroll
        for (int j = 0; j < 4; ++j) {
          int row = m0 + wm * (MF * 16) + mi * 16 + hi * 4 + j;
          int col = n0 + wn * 64 + nf * 16 + lo;
          C[(size_t)row * N + col] = acc[mi][nf][j];
        }
  } else {
    int which = n0 >> 10;                     // block-uniform (1024 % 256 == 0)
    int cb0 = (n0 & 1023) + wn * 64;
    if (which == 2) {                         // V: transposed, j-contiguous h4
      #pragma unroll
      for (int mi = 0; mi < MF; ++mi) {
        int row0 = m0 + wm * (MF * 16) + mi * 16 + hi * 4;
        int bb = row0 >> 11, ss0 = row0 & 2047;
        #pragma unroll
        for (int nf = 0; nf < 4; ++nf) {
          int col = cb0 + nf * 16 + lo;
          int hh = col >> 6, hd = col & 63;
          h4 o4;
          o4[0] = (_Float16)acc[mi][nf][0]; o4[1] = (_Float16)acc[mi][nf][1];
          o4[2] = (_Float16)acc[mi][nf][2]; o4[3] = (_Float16)acc[mi][nf][3];
          *(h4*)(Vo + (size_t)(bb * 16 + hh) * 131072 + (size_t)hd * 2048 + ss0) = o4;
        }
      }
    } else {
      _Float16* Dst = (which == 0) ? Qo : Ko;
      float qs = (which == 0) ? 0.1803368801111137f : 1.0f;   // 1/8 * log2(e)
      #pragma unroll
      for (int mi = 0; mi < MF; ++mi)
        #pragma unroll
        for (int nf = 0; nf < 4; ++nf)
          #pragma unroll
          for (int j = 0; j < 4; ++j) {
            int row = m0 + wm * (MF * 16) + mi * 16 + hi * 4 + j;
            int col = cb0 + nf * 16 + lo;
            int hh = col >> 6, hd = col & 63;
            int bb = row >> 11, ss = row & 2047;
            Dst[(size_t)(bb * 16 + hh) * 131072 + (size_t)ss * 64 + hd] =
                (_Float16)(acc[mi][nf][j] * qs);
          }
    }
  }
}

// ---------------- causal flash attention, HD=64, S=2048 ----------------------
// grid 2048: bh = bid&63 (XCD = bh%8), qi = 31-(bid>>6) (longest first).
// Block = 4 waves x 16 q-rows = QBLK 64 (256 threads); KVBLK=64, dbuf.
// 32 KB LDS -> 5 resident blocks/CU = 5 independent barrier groups.
// K rows sigma-PERMUTED in LDS (per-lane gload_lds source rows):
// sigma(r) = ((r&0x1C)<<1)|(r&3), sigma(r+32)=sigma(r)+4. Lane (hi,lo) reg j
// of QK^T frag kf holds S at global k = (kf&1)*32 + hi*8 + (kf>>1)*4 + j ==
// its PV B-fragment slots -> P stays in-lane (cvt_pkrtz only, no cross-lane).
// voff == koff reindexed. Defer-max THR=8 (exp2 domain).
__global__ __launch_bounds__(256) void attn_kernel(
    const _Float16* __restrict__ Q, const _Float16* __restrict__ Kb,
    const _Float16* __restrict__ Vb, _Float16* __restrict__ O)
{
  __shared__ _Float16 Kl[2 * 4096];   // [buf][sigma-row 64][chunk^row 8][8]
  __shared__ _Float16 Vl[2 * 4096];   // [buf][hd 64][chunk^row 8][8] (V^T)

  int bid = blockIdx.x;
  int bh = bid & 63, qi = 31 - (bid >> 6);
  int t = threadIdx.x, w = t >> 6, l = t & 63, lo = l & 15, hi = l >> 4;
  const size_t hoff = (size_t)bh * 131072;
  const _Float16* Kg = Kb + hoff;
  const _Float16* Vg = Vb + hoff;     // V^T: [64 hd][2048 s]
  int bb = bh >> 4, hh = bh & 15;

  // ---- staging: 256 threads cover rows {rs, rs+32} x 8 chunks ----
  int rs = t >> 3, cs = t & 7;        // LDS row 0..31 (+32), chunk 0..7
  int sw_ = (cs ^ (rs & 7)) * 8;
  int sigma = ((rs & 0x1C) << 1) | (rs & 3);      // K source-row permutation
  int srcK0 = sigma * 64 + sw_, srcK1 = srcK0 + 256;   // sigma(rs+32)=sigma+4
  int srcV0 = rs * 2048 + sw_,  srcV1 = srcV0 + 65536;
  _Float16* kd0 = Kl + w * 512;       // wave-uniform dest base
  _Float16* vd0 = Vl + w * 512;

  // ---- fragment offsets: QK uses koff[kf][0/1], PV uses koff[df][ks] ----
  int koff[4][2];
  #pragma unroll
  for (int kf = 0; kf < 4; ++kf) {
    int row = kf * 16 + lo;
    koff[kf][0] = row * 64 + ((hi       ^ (row & 7)) * 8);
    koff[kf][1] = row * 64 + (((4 + hi) ^ (row & 7)) * 8);
  }

  h8 ones;
  #pragma unroll
  for (int e = 0; e < 8; ++e) ones[e] = (_Float16)1.0f;

  int qb = qi * 64 + w * 16;
  const _Float16* Qp = Q + hoff + (size_t)(qb + lo) * 64 + hi * 8;
  h8 qf0 = *(const h8*)(Qp);
  h8 qf1 = *(const h8*)(Qp + 32);

  f4 acc[4] = {};
  float m_run = -1e30f, l_run = 0.f;
  int nkt = qi + 1;

#define STAGE(buf, kt) do {                                                   \
    const _Float16* Kt_ = Kg + (size_t)(kt) * 4096;                           \
    const _Float16* Vt_ = Vg + (size_t)(kt) * 64;                             \
    gload16(Kt_ + srcK0, kd0 + (buf) * 4096);                                 \
    gload16(Kt_ + srcK1, kd0 + (buf) * 4096 + 2048);                          \
    gload16(Vt_ + srcV0, vd0 + (buf) * 4096);                                 \
    gload16(Vt_ + srcV1, vd0 + (buf) * 4096 + 2048);                          \
  } while (0)

  STAGE(0, 0);
  asm volatile("s_waitcnt vmcnt(0)" ::: "memory");
  __syncthreads();

  #pragma unroll 1
  for (int kt = 0; kt < nkt; ++kt) {
    int buf = kt & 1;
    if (kt + 1 < nkt) STAGE(buf ^ 1, kt + 1);
    const _Float16* Kc = Kl + buf * 4096;
    const _Float16* Vc = Vl + buf * 4096;

    f4 sc[4] = {};
    __builtin_amdgcn_s_setprio(1);
    #pragma unroll
    for (int kf = 0; kf < 4; ++kf) {
      h8 k0 = *(const h8*)(Kc + koff[kf][0]);
      h8 k1 = *(const h8*)(Kc + koff[kf][1]);
      sc[kf] = mfma16(k0, qf0, sc[kf]);
      sc[kf] = mfma16(k1, qf1, sc[kf]);
    }
    __builtin_amdgcn_s_setprio(0);

    if (kt == nkt - 1) {                     // diagonal tile
      int qg = qb + lo;
      #pragma unroll
      for (int kf = 0; kf < 4; ++kf) {
        int kgb = kt * 64 + ((kf & 1) << 5) + ((kf >> 1) << 2) + hi * 8;
        #pragma unroll
        for (int j = 0; j < 4; ++j)
          if (kgb + j > qg) sc[kf][j] = -1e30f;
      }
    }

    {
      f4 m4;
      #pragma unroll
      for (int c = 0; c < 4; ++c)
        m4[c] = fmaxf(max3f(sc[0][c], sc[1][c], sc[2][c]), sc[3][c]);
      float mx = fmaxf(max3f(m4[0], m4[1], m4[2]), m4[3]);
      if (!__all(mx <= m_run + 8.f)) {       // defer-max: rare path
        mx = fmaxf(mx, __shfl_xor(mx, 16));
        mx = fmaxf(mx, __shfl_xor(mx, 32));
        float mn = fmaxf(m_run, mx);
        float cr = exp2f(m_run - mn);
        m_run = mn;
        l_run *= cr;
        #pragma unroll
        for (int df = 0; df < 4; ++df) {
          acc[df][0] *= cr; acc[df][1] *= cr;
          acc[df][2] *= cr; acc[df][3] *= cr;
        }
      }
    }

    f4 ls = {};
    #pragma unroll
    for (int ks = 0; ks < 2; ++ks) {
      u4 tw;
      tw[0] = cvtpku(exp2f(sc[ks    ][0] - m_run),
                     exp2f(sc[ks    ][1] - m_run));
      tw[1] = cvtpku(exp2f(sc[ks    ][2] - m_run),
                     exp2f(sc[ks    ][3] - m_run));
      tw[2] = cvtpku(exp2f(sc[2 + ks][0] - m_run),
                     exp2f(sc[2 + ks][1] - m_run));
      tw[3] = cvtpku(exp2f(sc[2 + ks][2] - m_run),
                     exp2f(sc[2 + ks][3] - m_run));
      h8 pf = __builtin_bit_cast(h8, tw);
      ls = mfma16(ones, pf, ls);
      __builtin_amdgcn_s_setprio(1);
      #pragma unroll
      for (int df = 0; df < 4; ++df) {
        h8 vf = *(const h8*)(Vc + koff[df][ks]);
        acc[df] = mfma16(vf, pf, acc[df]);
      }
      __builtin_amdgcn_s_setprio(0);
    }
    l_run += ls[0];

    asm volatile("s_waitcnt vmcnt(0)" ::: "memory");
    __syncthreads();
  }

  // epilogue: lane (hi,lo) holds O[q = qb+lo][d = df*16+hi*4+j]
  {
    float inv = 1.0f / l_run;
    int q = qb + lo;
    _Float16* Op = O + ((size_t)(bb * 2048 + q)) * 1024 + hh * 64 + (hi << 2);
    #pragma unroll
    for (int df = 0; df < 4; ++df) {
      h4 o4;
      o4[0] = (_Float16)(acc[df][0] * inv);
      o4[1] = (_Float16)(acc[df][1] * inv);
      o4[2] = (_Float16)(acc[df][2] * inv);
      o4[3] = (_Float16)(acc[df][3] * inv);
      *(h4*)(Op + df * 16) = o4;
    }
  }
#undef STAGE
}

extern "C" void kernel_launch(void* const* d_in, const int* in_sizes, int n_in,
                              void* d_out, int out_size, void* d_ws, size_t ws_size,
                              hipStream_t stream)
{
  const float* x  = (const float*)d_in[0];
  const float* wq = (const float*)d_in[1];
  const float* wk = (const float*)d_in[2];
  const float* wv = (const float*)d_in[3];
  const float* wo = (const float*)d_in[4];
  // d_in[5] = causal mask: implemented analytically.

  char* ws = (char*)d_ws;
  _Float16* xb   = (_Float16*)(ws);                  // 16 MB, reused as Ob later
  _Float16* wqkv = (_Float16*)(ws + (16u << 20));    //  6 MB
  _Float16* wob  = (_Float16*)(ws + (22u << 20));    //  2 MB
  _Float16* Qb   = (_Float16*)(ws + (24u << 20));    // 16 MB
  _Float16* Kb   = (_Float16*)(ws + (40u << 20));    // 16 MB
  _Float16* Vb   = (_Float16*)(ws + (56u << 20));    // 16 MB (transposed)
  _Float16* Ob   = xb;                               // xb dead after QKV GEMM

  cvt_all<<<12288, 256, 0, stream>>>(x, wq, wk, wv, wo, xb, wqkv, wob);
  gemmT<1, 4><<<64 * 12, 512, 0, stream>>>(xb, wqkv, nullptr, Qb, Kb, Vb, 3072, 12);
  attn_kernel<<<2048, 256, 0, stream>>>(Qb, Kb, Vb, Ob);
  gemmT<0, 4><<<64 * 4, 512, 0, stream>>>(Ob, wob, (float*)d_out,
                                          nullptr, nullptr, nullptr, 1024, 4);
}

// Round 13
// 160.984 us; speedup vs baseline: 1.0748x; 1.0748x over previous
//
#include <hip/hip_runtime.h>

typedef float    f4 __attribute__((ext_vector_type(4)));
typedef _Float16 h8 __attribute__((ext_vector_type(8)));
typedef _Float16 h4 __attribute__((ext_vector_type(4)));
typedef _Float16 h2 __attribute__((ext_vector_type(2)));
typedef unsigned u4 __attribute__((ext_vector_type(4)));

#define DEV static __device__ __forceinline__

DEV f4 mfma16(h8 a, h8 b, f4 c) {
  return __builtin_amdgcn_mfma_f32_16x16x32_f16(a, b, c, 0, 0, 0);
}

DEV void gload16(const void* g, void* lds) {
  __builtin_amdgcn_global_load_lds((__attribute__((address_space(1))) void*)g,
                                   (__attribute__((address_space(3))) void*)lds,
                                   16, 0, 0);
}

DEV unsigned cvtpku(float a, float b) {
  return __builtin_bit_cast(unsigned, __builtin_amdgcn_cvt_pkrtz(a, b));
}

DEV float max3f(float a, float b, float c) {
  float d;
  asm("v_max3_f32 %0, %1, %2, %3" : "=v"(d) : "v"(a), "v"(b), "v"(c));
  return d;
}

// ---------------- fp32 -> fp16 conversion (x + packed weights) ----------------
__global__ __launch_bounds__(256) void cvt_all(
    const float* __restrict__ x,  const float* __restrict__ wq,
    const float* __restrict__ wk, const float* __restrict__ wv,
    const float* __restrict__ wo,
    _Float16* __restrict__ xb, _Float16* __restrict__ wqkv, _Float16* __restrict__ wob)
{
  int b = blockIdx.x;
  const float* src; _Float16* dst; int i4;
  if      (b < 8192)  { src = x;  dst = xb;                 i4 = b * 256; }
  else if (b < 9216)  { src = wq; dst = wqkv;               i4 = (b - 8192)  * 256; }
  else if (b < 10240) { src = wk; dst = wqkv + (1u << 20);  i4 = (b - 9216)  * 256; }
  else if (b < 11264) { src = wv; dst = wqkv + (2u << 20);  i4 = (b - 10240) * 256; }
  else                { src = wo; dst = wob;                i4 = (b - 11264) * 256; }
  i4 += threadIdx.x;
  f4 v = ((const f4*)src)[i4];
  h4 o;
  o[0] = (_Float16)v[0]; o[1] = (_Float16)v[1];
  o[2] = (_Float16)v[2]; o[3] = (_Float16)v[3];
  ((h4*)dst)[i4] = o;
}

// ===== 8-phase GEMM: C[M,N] = A[M,K] * Bt[N,K]^T, BM=MF*32, BN=NF*64 =======
// 8 waves (2M x 4N). Double-buffered quadrant regions; counted vmcnt (never 0
// mid-loop; generalized: ALD=A-loads, BLD=B-loads per region, L=2(ALD+BLD));
// chunk^row&7 swizzle via pre-swizzled global source; setprio on MFMA.
// B region layout: NF=4 -> region QN = rows == QN*32 (mod 64), 4x32-row panels;
//                  NF=2 -> region QN = rows == QN*16 (mod 32), 4x16-row panels
// (read side: wave wn's fragment-group D lives in region D at panel wn).
// MODE 0: fp32 C row-major. MODE 1: Q(scaled)/K [B,H,S,HD], V^T [B,H,HD,S].
template<int MODE, int MF, int NF>
__global__ __launch_bounds__(512) void gemmT(
    const _Float16* __restrict__ A, const _Float16* __restrict__ Bt,
    float* __restrict__ C,
    _Float16* __restrict__ Qo, _Float16* __restrict__ Ko, _Float16* __restrict__ Vo,
    int N, int Nt)
{
  constexpr int ASZ = MF * 16 * 64;       // A quadrant region (f16)
  constexpr int BSZ = NF * 32 * 64;       // B quadrant region (f16)
  constexpr int ALD = (MF == 8) ? 2 : 1;  // gloads per A region
  constexpr int BLD = NF / 2;             // gloads per B region
  constexpr int L   = 2 * (ALD + BLD);    // gloads per K-tile
  constexpr int V1  = (3 * L) / 2;        // steady @P1/P3/P5/P7
  constexpr int V2  = 3 * ALD + 2 * BLD;  // steady @P2/P6
  constexpr int VL3 = L;                  // last-iter drains
  constexpr int VL5 = L / 2;
  constexpr int VL6 = L - ALD - 2 * BLD;
  __shared__ _Float16 Al[4 * ASZ];    // [buf][q]
  __shared__ _Float16 Bl[4 * BSZ];    // [buf][qn]

  int bid = blockIdx.x;
  int cpx = gridDim.x >> 3;                  // grid % 8 == 0 (bijective)
  bid = (bid & 7) * cpx + (bid >> 3);        // XCD-chunked swizzle
  int tm = bid / Nt, tn = bid - tm * Nt;
  int m0 = tm * (MF * 32), n0 = tn * (NF * 64);

  int t = threadIdx.x, w = t >> 6, l = t & 63, lo = l & 15, hi = l >> 4;
  int wm = w >> 2, wn = w & 3;

  // ---- staging sources (pre-swizzled chunk: involution chunk^=(row&7)) ----
  int rsc = t >> 3;                          // 0..63
  int csrc = ((t & 7) ^ (rsc & 7)) * 8;
  const _Float16 *As[2][2], *Bs[2][2];
  #pragma unroll
  for (int q = 0; q < 2; ++q) {
    if (MF == 8) {
      As[q][0] = A + (size_t)(m0 + q * 64 + rsc) * 1024 + csrc;
      As[q][1] = A + (size_t)(m0 + 128 + q * 64 + rsc) * 1024 + csrc;
    } else {
      As[q][0] = A + (size_t)(m0 + (t >> 8) * 64 + q * 32 + (rsc & 31)) * 1024 + csrc;
      As[q][1] = As[q][0];
    }
    #pragma unroll
    for (int h = 0; h < 2; ++h) {
      if (NF == 4)
        Bs[q][h] = Bt + (size_t)(n0 + (2 * h + (t >> 8)) * 64 + q * 32 + (rsc & 31)) * 1024 + csrc;
      else  // NF == 2: panel rsc>>4 (16 rows), region q interleaved mod 32
        Bs[q][h] = Bt + (size_t)(n0 + (rsc >> 4) * 32 + q * 16 + (rsc & 15)) * 1024 + csrc;
    }
  }
  _Float16* Adst = Al + w * 512;
  _Float16* Bdst = Bl + w * 512;

  // ---- fragment read offsets (f16 units) ----
  int awoff = wm * (MF * 8 * 64) + lo * 64;
  int bwoff = wn * (NF * 512) + lo * 64;
  int s0 = (hi ^ (lo & 7)) * 8;
  int s1 = ((4 + hi) ^ (lo & 7)) * 8;

  f4 acc[MF][NF] = {};
  h8 ar[MF / 2][2], br[2][NF / 2][2];

#define VMW(n)  asm volatile("s_waitcnt vmcnt(%0)" :: "n"(n) : "memory")
#define BARR    __builtin_amdgcn_s_barrier()
#define LGKM0   do { asm volatile("s_waitcnt lgkmcnt(0)" ::: "memory"); \
                     __builtin_amdgcn_sched_barrier(0); } while (0)
#define STA(BUF, Q, KO) do { \
    gload16(As[Q][0] + (KO), Adst + ((BUF) * 2 + (Q)) * ASZ); \
    if (MF == 8) gload16(As[Q][1] + (KO), Adst + ((BUF) * 2 + (Q)) * ASZ + 4096); \
  } while (0)
#define STB(BUF, QN, KO) do { \
    gload16(Bs[QN][0] + (KO), Bdst + ((BUF) * 2 + (QN)) * BSZ); \
    if (NF == 4) gload16(Bs[QN][1] + (KO), Bdst + ((BUF) * 2 + (QN)) * BSZ + 4096); \
  } while (0)
#define RDA(BUF, Q) do { \
    const _Float16* p_ = Al + ((BUF) * 2 + (Q)) * ASZ + awoff; \
    _Pragma("unroll") \
    for (int f_ = 0; f_ < MF / 2; ++f_) { \
      ar[f_][0] = *(const h8*)(p_ + f_ * 1024 + s0); \
      ar[f_][1] = *(const h8*)(p_ + f_ * 1024 + s1); } \
  } while (0)
#define RDB(BUF, QN, D) do { \
    const _Float16* p_ = Bl + ((BUF) * 2 + (QN)) * BSZ + bwoff; \
    _Pragma("unroll") \
    for (int g_ = 0; g_ < NF / 2; ++g_) { \
      br[D][g_][0] = *(const h8*)(p_ + g_ * 1024 + s0); \
      br[D][g_][1] = *(const h8*)(p_ + g_ * 1024 + s1); } \
  } while (0)
#define MM(MH, D) do { \
    __builtin_amdgcn_s_setprio(1); \
    _Pragma("unroll") \
    for (int f_ = 0; f_ < MF / 2; ++f_) \
      _Pragma("unroll") \
      for (int g_ = 0; g_ < NF / 2; ++g_) { \
        acc[(MH) * (MF / 2) + f_][(D) * (NF / 2) + g_] = \
            mfma16(ar[f_][0], br[D][g_][0], acc[(MH) * (MF / 2) + f_][(D) * (NF / 2) + g_]); \
        acc[(MH) * (MF / 2) + f_][(D) * (NF / 2) + g_] = \
            mfma16(ar[f_][1], br[D][g_][1], acc[(MH) * (MF / 2) + f_][(D) * (NF / 2) + g_]); } \
    __builtin_amdgcn_s_setprio(0); \
    __builtin_amdgcn_sched_barrier(0); \
  } while (0)

  // prologue: tiles 0 (buf0) and 1 (buf1), region order Aq0,Bq0 | Bq1 | Aq1
  STA(0, 0, 0);  STB(0, 0, 0);  STB(0, 1, 0);  STA(0, 1, 0);
  STA(1, 0, 64); STB(1, 0, 64); STB(1, 1, 64); STA(1, 1, 64);

  int kof = 128;                         // element offset of tile 2it+2
  #pragma unroll 1
  for (int it = 0; it < 7; ++it) {       // NT/2 - 1 steady iterations
    VMW(V1); BARR; RDA(0, 0); RDB(0, 0, 0); LGKM0; MM(0, 0);
    VMW(V2); BARR; RDB(0, 1, 1); STA(0, 0, kof); STB(0, 0, kof); LGKM0; MM(0, 1);
    VMW(V1); BARR; RDA(0, 1); STB(0, 1, kof); LGKM0; MM(1, 1);
    BARR; STA(0, 1, kof); MM(1, 0);
    VMW(V1); BARR; RDA(1, 0); RDB(1, 0, 0); LGKM0; MM(0, 0);
    VMW(V2); BARR; RDB(1, 1, 1); STA(1, 0, kof + 64); STB(1, 0, kof + 64); LGKM0; MM(0, 1);
    VMW(V1); BARR; RDA(1, 1); STB(1, 1, kof + 64); LGKM0; MM(1, 1);
    BARR; STA(1, 1, kof + 64); MM(1, 0);
    kof += 128;
  }
  // last iteration: no staging, drain counts
  VMW(V1);  BARR; RDA(0, 0); RDB(0, 0, 0); LGKM0; MM(0, 0);
  VMW(V2);  BARR; RDB(0, 1, 1); LGKM0; MM(0, 1);
  VMW(VL3); BARR; RDA(0, 1); LGKM0; MM(1, 1);
  BARR; MM(1, 0);
  VMW(VL5); BARR; RDA(1, 0); RDB(1, 0, 0); LGKM0; MM(0, 0);
  VMW(VL6); BARR; RDB(1, 1, 1); LGKM0; MM(0, 1);
  VMW(0);   BARR; RDA(1, 1); LGKM0; MM(1, 1);
  BARR; MM(1, 0);

#undef VMW
#undef BARR
#undef LGKM0
#undef STA
#undef STB
#undef RDA
#undef RDB
#undef MM

  // ---- epilogue ----
  if (MODE == 0) {
    #pragma unroll
    for (int mi = 0; mi < MF; ++mi)
      #pragma unroll
      for (int nf = 0; nf < NF; ++nf)
        #pragma unroll
        for (int j = 0; j < 4; ++j) {
          int row = m0 + wm * (MF * 16) + mi * 16 + hi * 4 + j;
          int col = n0 + wn * (NF * 16) + nf * 16 + lo;
          C[(size_t)row * N + col] = acc[mi][nf][j];
        }
  } else {
    int which = n0 >> 10;                     // block-uniform (1024 % BN == 0)
    int cb0 = (n0 & 1023) + wn * (NF * 16);
    if (which == 2) {                         // V: transposed, j-contiguous h4
      #pragma unroll
      for (int mi = 0; mi < MF; ++mi) {
        int row0 = m0 + wm * (MF * 16) + mi * 16 + hi * 4;
        int bb = row0 >> 11, ss0 = row0 & 2047;
        #pragma unroll
        for (int nf = 0; nf < NF; ++nf) {
          int col = cb0 + nf * 16 + lo;
          int hh = col >> 6, hd = col & 63;
          h4 o4;
          o4[0] = (_Float16)acc[mi][nf][0]; o4[1] = (_Float16)acc[mi][nf][1];
          o4[2] = (_Float16)acc[mi][nf][2]; o4[3] = (_Float16)acc[mi][nf][3];
          *(h4*)(Vo + (size_t)(bb * 16 + hh) * 131072 + (size_t)hd * 2048 + ss0) = o4;
        }
      }
    } else {
      _Float16* Dst = (which == 0) ? Qo : Ko;
      float qs = (which == 0) ? 0.1803368801111137f : 1.0f;   // 1/8 * log2(e)
      #pragma unroll
      for (int mi = 0; mi < MF; ++mi)
        #pragma unroll
        for (int nf = 0; nf < NF; ++nf)
          #pragma unroll
          for (int j = 0; j < 4; ++j) {
            int row = m0 + wm * (MF * 16) + mi * 16 + hi * 4 + j;
            int col = cb0 + nf * 16 + lo;
            int hh = col >> 6, hd = col & 63;
            int bb = row >> 11, ss = row & 2047;
            Dst[(size_t)(bb * 16 + hh) * 131072 + (size_t)ss * 64 + hd] =
                (_Float16)(acc[mi][nf][j] * qs);
          }
    }
  }
}

// ---------------- causal flash attention, HD=64, S=2048 (R10 config) ---------
// grid 1024: bh = bid&63 (XCD = bh%8), qi = 15-(bid>>6) (longest first).
// Block = 8 waves x 16 q-rows = QBLK 128 (512 threads); KVBLK=64, dbuf.
// K rows sigma-PERMUTED in LDS (per-lane gload_lds source rows):
// sigma(r) = ((r&0x1C)<<1)|(r&3)|((r&32)>>3). Lane (hi,lo) reg j of QK^T
// frag kf holds S at global k = (kf&1)*32 + hi*8 + (kf>>1)*4 + j == its PV
// B-fragment slots -> P stays in-lane (cvt_pkrtz only, no cross-lane).
// voff == koff reindexed. Defer-max THR=8 (exp2 domain).
__global__ __launch_bounds__(512, 4) void attn_kernel(
    const _Float16* __restrict__ Q, const _Float16* __restrict__ Kb,
    const _Float16* __restrict__ Vb, _Float16* __restrict__ O)
{
  __shared__ _Float16 Kl[2 * 4096];   // [buf][sigma-row 64][chunk^row 8][8]
  __shared__ _Float16 Vl[2 * 4096];   // [buf][hd 64][chunk^row 8][8] (V^T)

  int bid = blockIdx.x;
  int bh = bid & 63, qi = 15 - (bid >> 6);
  int t = threadIdx.x, w = t >> 6, l = t & 63, lo = l & 15, hi = l >> 4;
  const size_t hoff = (size_t)bh * 131072;
  const _Float16* Kg = Kb + hoff;
  const _Float16* Vg = Vb + hoff;     // V^T: [64 hd][2048 s]
  int bb = bh >> 4, hh = bh & 15;

  // ---- staging: thread t covers LDS 16B-chunk t (1 K + 1 V gload) ----
  int rs = t >> 3, cs = t & 7;        // LDS row 0..63, chunk 0..7
  int sw_ = (cs ^ (rs & 7)) * 8;
  int sigma = ((rs & 0x1C) << 1) | (rs & 3) | ((rs & 32) >> 3);
  int srcK = sigma * 64 + sw_;
  int srcV = rs * 2048 + sw_;
  _Float16* kd0 = Kl + w * 512;       // wave-uniform dest base
  _Float16* vd0 = Vl + w * 512;

  // ---- fragment offsets: QK uses koff[kf][0/1], PV uses koff[df][ks] ----
  int koff[4][2];
  #pragma unroll
  for (int kf = 0; kf < 4; ++kf) {
    int row = kf * 16 + lo;
    koff[kf][0] = row * 64 + ((hi       ^ (row & 7)) * 8);
    koff[kf][1] = row * 64 + (((4 + hi) ^ (row & 7)) * 8);
  }

  h8 ones;
  #pragma unroll
  for (int e = 0; e < 8; ++e) ones[e] = (_Float16)1.0f;

  int qb = qi * 128 + w * 16;
  const _Float16* Qp = Q + hoff + (size_t)(qb + lo) * 64 + hi * 8;
  h8 qf0 = *(const h8*)(Qp);
  h8 qf1 = *(const h8*)(Qp + 32);

  f4 acc[4] = {};
  float m_run = -1e30f, l_run = 0.f;
  int nkt = 2 * qi + 2;

#define STAGE(buf, kt) do {                                                   \
    const _Float16* Kt_ = Kg + (size_t)(kt) * 4096;                           \
    const _Float16* Vt_ = Vg + (size_t)(kt) * 64;                             \
    gload16(Kt_ + srcK, kd0 + (buf) * 4096);                                  \
    gload16(Vt_ + srcV, vd0 + (buf) * 4096);                                  \
  } while (0)

#define ITER(kt, buf) do {                                                    \
    if ((kt) + 1 < nkt) STAGE(buf ^ 1, (kt) + 1);                             \
    const _Float16* Kc = Kl + (buf) * 4096;                                   \
    const _Float16* Vc = Vl + (buf) * 4096;                                   \
    f4 sc[4] = {};                                                            \
    __builtin_amdgcn_s_setprio(1);                                            \
    _Pragma("unroll")                                                         \
    for (int kf = 0; kf < 4; ++kf) {                                          \
      h8 k0 = *(const h8*)(Kc + koff[kf][0]);                                 \
      h8 k1 = *(const h8*)(Kc + koff[kf][1]);                                 \
      sc[kf] = mfma16(k0, qf0, sc[kf]);                                       \
      sc[kf] = mfma16(k1, qf1, sc[kf]);                                       \
    }                                                                         \
    __builtin_amdgcn_s_setprio(0);                                            \
    if ((kt) >= 2 * qi) {                                                     \
      int qg = qb + lo;                                                       \
      _Pragma("unroll")                                                       \
      for (int kf = 0; kf < 4; ++kf) {                                        \
        int kgb = (kt) * 64 + ((kf & 1) << 5) + ((kf >> 1) << 2) + hi * 8;    \
        _Pragma("unroll")                                                     \
        for (int j = 0; j < 4; ++j)                                           \
          if (kgb + j > qg) sc[kf][j] = -1e30f;                               \
      }                                                                       \
    }                                                                         \
    {                                                                         \
      f4 m4;                                                                  \
      _Pragma("unroll")                                                       \
      for (int c = 0; c < 4; ++c)                                             \
        m4[c] = fmaxf(max3f(sc[0][c], sc[1][c], sc[2][c]), sc[3][c]);         \
      float mx = fmaxf(max3f(m4[0], m4[1], m4[2]), m4[3]);                    \
      if (!__all(mx <= m_run + 8.f)) {        /* defer-max: rare path */      \
        mx = fmaxf(mx, __shfl_xor(mx, 16));                                   \
        mx = fmaxf(mx, __shfl_xor(mx, 32));                                   \
        float mn = fmaxf(m_run, mx);                                          \
        float cr = exp2f(m_run - mn);                                         \
        m_run = mn;                                                           \
        l_run *= cr;                                                          \
        _Pragma("unroll")                                                     \
        for (int df = 0; df < 4; ++df) {                                      \
          acc[df][0] *= cr; acc[df][1] *= cr;                                 \
          acc[df][2] *= cr; acc[df][3] *= cr;                                 \
        }                                                                     \
      }                                                                       \
    }                                                                         \
    f4 ls = {};                                                               \
    _Pragma("unroll")                                                         \
    for (int ks = 0; ks < 2; ++ks) {                                          \
      u4 tw;                                                                  \
      tw[0] = cvtpku(exp2f(sc[ks    ][0] - m_run),                            \
                     exp2f(sc[ks    ][1] - m_run));                           \
      tw[1] = cvtpku(exp2f(sc[ks    ][2] - m_run),                            \
                     exp2f(sc[ks    ][3] - m_run));                           \
      tw[2] = cvtpku(exp2f(sc[2 + ks][0] - m_run),                            \
                     exp2f(sc[2 + ks][1] - m_run));                           \
      tw[3] = cvtpku(exp2f(sc[2 + ks][2] - m_run),                            \
                     exp2f(sc[2 + ks][3] - m_run));                           \
      h8 pf = __builtin_bit_cast(h8, tw);                                     \
      ls = mfma16(ones, pf, ls);                                              \
      __builtin_amdgcn_s_setprio(1);                                          \
      _Pragma("unroll")                                                       \
      for (int df = 0; df < 4; ++df) {                                        \
        h8 vf = *(const h8*)(Vc + koff[df][ks]);                              \
        acc[df] = mfma16(vf, pf, acc[df]);                                    \
      }                                                                       \
      __builtin_amdgcn_s_setprio(0);                                          \
    }                                                                         \
    l_run += ls[0];                                                           \
    asm volatile("s_waitcnt vmcnt(0)" ::: "memory");                          \
    __syncthreads();                                                          \
  } while (0)

  STAGE(0, 0);
  asm volatile("s_waitcnt vmcnt(0)" ::: "memory");
  __syncthreads();

  for (int kt = 0; kt < nkt; kt += 2) {
    ITER(kt, 0);
    ITER(kt + 1, 1);
  }

  // epilogue: lane (hi,lo) holds O[q = qb+lo][d = df*16+hi*4+j]
  {
    float inv = 1.0f / l_run;
    int q = qb + lo;
    _Float16* Op = O + ((size_t)(bb * 2048 + q)) * 1024 + hh * 64 + (hi << 2);
    #pragma unroll
    for (int df = 0; df < 4; ++df) {
      h4 o4;
      o4[0] = (_Float16)(acc[df][0] * inv);
      o4[1] = (_Float16)(acc[df][1] * inv);
      o4[2] = (_Float16)(acc[df][2] * inv);
      o4[3] = (_Float16)(acc[df][3] * inv);
      *(h4*)(Op + df * 16) = o4;
    }
  }
#undef ITER
#undef STAGE
}

extern "C" void kernel_launch(void* const* d_in, const int* in_sizes, int n_in,
                              void* d_out, int out_size, void* d_ws, size_t ws_size,
                              hipStream_t stream)
{
  const float* x  = (const float*)d_in[0];
  const float* wq = (const float*)d_in[1];
  const float* wk = (const float*)d_in[2];
  const float* wv = (const float*)d_in[3];
  const float* wo = (const float*)d_in[4];
  // d_in[5] = causal mask: implemented analytically.

  char* ws = (char*)d_ws;
  _Float16* xb   = (_Float16*)(ws);                  // 16 MB, reused as Ob later
  _Float16* wqkv = (_Float16*)(ws + (16u << 20));    //  6 MB
  _Float16* wob  = (_Float16*)(ws + (22u << 20));    //  2 MB
  _Float16* Qb   = (_Float16*)(ws + (24u << 20));    // 16 MB
  _Float16* Kb   = (_Float16*)(ws + (40u << 20));    // 16 MB
  _Float16* Vb   = (_Float16*)(ws + (56u << 20));    // 16 MB (transposed)
  _Float16* Ob   = xb;                               // xb dead after QKV GEMM

  cvt_all<<<12288, 256, 0, stream>>>(x, wq, wk, wv, wo, xb, wqkv, wob);
  gemmT<1, 8, 4><<<32 * 12, 512, 0, stream>>>(xb, wqkv, nullptr, Qb, Kb, Vb, 3072, 12);
  attn_kernel<<<1024, 512, 0, stream>>>(Qb, Kb, Vb, Ob);
  gemmT<0, 4, 2><<<64 * 8, 512, 0, stream>>>(Ob, wob, (float*)d_out,
                                             nullptr, nullptr, nullptr, 1024, 8);
}

// Round 14
// 160.011 us; speedup vs baseline: 1.0813x; 1.0061x over previous
//
#include <hip/hip_runtime.h>

typedef float    f4 __attribute__((ext_vector_type(4)));
typedef _Float16 h8 __attribute__((ext_vector_type(8)));
typedef _Float16 h4 __attribute__((ext_vector_type(4)));
typedef _Float16 h2 __attribute__((ext_vector_type(2)));
typedef unsigned u4 __attribute__((ext_vector_type(4)));

#define DEV static __device__ __forceinline__

DEV f4 mfma16(h8 a, h8 b, f4 c) {
  return __builtin_amdgcn_mfma_f32_16x16x32_f16(a, b, c, 0, 0, 0);
}

DEV void gload16(const void* g, void* lds) {
  __builtin_amdgcn_global_load_lds((__attribute__((address_space(1))) void*)g,
                                   (__attribute__((address_space(3))) void*)lds,
                                   16, 0, 0);
}

DEV unsigned cvtpku(float a, float b) {
  return __builtin_bit_cast(unsigned, __builtin_amdgcn_cvt_pkrtz(a, b));
}

DEV float max3f(float a, float b, float c) {
  float d;
  asm("v_max3_f32 %0, %1, %2, %3" : "=v"(d) : "v"(a), "v"(b), "v"(c));
  return d;
}

// ---------------- fp32 -> fp16 conversion (x + packed weights) ----------------
__global__ __launch_bounds__(256) void cvt_all(
    const float* __restrict__ x,  const float* __restrict__ wq,
    const float* __restrict__ wk, const float* __restrict__ wv,
    const float* __restrict__ wo,
    _Float16* __restrict__ xb, _Float16* __restrict__ wqkv, _Float16* __restrict__ wob)
{
  int b = blockIdx.x;
  const float* src; _Float16* dst; int i4;
  if      (b < 8192)  { src = x;  dst = xb;                 i4 = b * 256; }
  else if (b < 9216)  { src = wq; dst = wqkv;               i4 = (b - 8192)  * 256; }
  else if (b < 10240) { src = wk; dst = wqkv + (1u << 20);  i4 = (b - 9216)  * 256; }
  else if (b < 11264) { src = wv; dst = wqkv + (2u << 20);  i4 = (b - 10240) * 256; }
  else                { src = wo; dst = wob;                i4 = (b - 11264) * 256; }
  i4 += threadIdx.x;
  f4 v = ((const f4*)src)[i4];
  h4 o;
  o[0] = (_Float16)v[0]; o[1] = (_Float16)v[1];
  o[2] = (_Float16)v[2]; o[3] = (_Float16)v[3];
  ((h4*)dst)[i4] = o;
}

// ===== 8-phase GEMM: C[M,N] = A[M,K] * Bt[N,K]^T, BM=MF*32, BN=NF*64 =======
// 8 waves (2M x 4N). Double-buffered quadrant regions; counted vmcnt (never 0
// mid-loop; generalized: ALD=A-loads, BLD=B-loads per region, L=2(ALD+BLD));
// chunk^row&7 swizzle via pre-swizzled global source; setprio on MFMA.
// B region layout: NF=4 -> region QN = rows == QN*32 (mod 64), 4x32-row panels;
//                  NF=2 -> region QN = rows == QN*16 (mod 32), 4x16-row panels
// (read side: wave wn's fragment-group D lives in region D at panel wn).
// MODE 0: fp32 C row-major. MODE 1: Q(scaled)/K [B,H,S,HD], V^T [B,H,HD,S].
template<int MODE, int MF, int NF>
__global__ __launch_bounds__(512) void gemmT(
    const _Float16* __restrict__ A, const _Float16* __restrict__ Bt,
    float* __restrict__ C,
    _Float16* __restrict__ Qo, _Float16* __restrict__ Ko, _Float16* __restrict__ Vo,
    int N, int Nt)
{
  constexpr int ASZ = MF * 16 * 64;       // A quadrant region (f16)
  constexpr int BSZ = NF * 32 * 64;       // B quadrant region (f16)
  constexpr int ALD = (MF == 8) ? 2 : 1;  // gloads per A region
  constexpr int BLD = NF / 2;             // gloads per B region
  constexpr int L   = 2 * (ALD + BLD);    // gloads per K-tile
  constexpr int V1  = (3 * L) / 2;        // steady @P1/P3/P5/P7
  constexpr int V2  = 3 * ALD + 2 * BLD;  // steady @P2/P6
  constexpr int VL3 = L;                  // last-iter drains
  constexpr int VL5 = L / 2;
  constexpr int VL6 = L - ALD - 2 * BLD;
  __shared__ _Float16 Al[4 * ASZ];    // [buf][q]
  __shared__ _Float16 Bl[4 * BSZ];    // [buf][qn]

  int bid = blockIdx.x;
  int cpx = gridDim.x >> 3;                  // grid % 8 == 0 (bijective)
  bid = (bid & 7) * cpx + (bid >> 3);        // XCD-chunked swizzle
  int tm = bid / Nt, tn = bid - tm * Nt;
  int m0 = tm * (MF * 32), n0 = tn * (NF * 64);

  int t = threadIdx.x, w = t >> 6, l = t & 63, lo = l & 15, hi = l >> 4;
  int wm = w >> 2, wn = w & 3;

  // ---- staging sources (pre-swizzled chunk: involution chunk^=(row&7)) ----
  int rsc = t >> 3;                          // 0..63
  int csrc = ((t & 7) ^ (rsc & 7)) * 8;
  const _Float16 *As[2][2], *Bs[2][2];
  #pragma unroll
  for (int q = 0; q < 2; ++q) {
    if (MF == 8) {
      As[q][0] = A + (size_t)(m0 + q * 64 + rsc) * 1024 + csrc;
      As[q][1] = A + (size_t)(m0 + 128 + q * 64 + rsc) * 1024 + csrc;
    } else {
      As[q][0] = A + (size_t)(m0 + (t >> 8) * 64 + q * 32 + (rsc & 31)) * 1024 + csrc;
      As[q][1] = As[q][0];
    }
    #pragma unroll
    for (int h = 0; h < 2; ++h) {
      if (NF == 4)
        Bs[q][h] = Bt + (size_t)(n0 + (2 * h + (t >> 8)) * 64 + q * 32 + (rsc & 31)) * 1024 + csrc;
      else  // NF == 2: panel rsc>>4 (16 rows), region q interleaved mod 32
        Bs[q][h] = Bt + (size_t)(n0 + (rsc >> 4) * 32 + q * 16 + (rsc & 15)) * 1024 + csrc;
    }
  }
  _Float16* Adst = Al + w * 512;
  _Float16* Bdst = Bl + w * 512;

  // ---- fragment read offsets (f16 units) ----
  int awoff = wm * (MF * 8 * 64) + lo * 64;
  int bwoff = wn * (NF * 512) + lo * 64;
  int s0 = (hi ^ (lo & 7)) * 8;
  int s1 = ((4 + hi) ^ (lo & 7)) * 8;

  f4 acc[MF][NF] = {};
  h8 ar[MF / 2][2], br[2][NF / 2][2];

#define VMW(n)  asm volatile("s_waitcnt vmcnt(%0)" :: "n"(n) : "memory")
#define BARR    __builtin_amdgcn_s_barrier()
#define LGKM0   do { asm volatile("s_waitcnt lgkmcnt(0)" ::: "memory"); \
                     __builtin_amdgcn_sched_barrier(0); } while (0)
#define STA(BUF, Q, KO) do { \
    gload16(As[Q][0] + (KO), Adst + ((BUF) * 2 + (Q)) * ASZ); \
    if (MF == 8) gload16(As[Q][1] + (KO), Adst + ((BUF) * 2 + (Q)) * ASZ + 4096); \
  } while (0)
#define STB(BUF, QN, KO) do { \
    gload16(Bs[QN][0] + (KO), Bdst + ((BUF) * 2 + (QN)) * BSZ); \
    if (NF == 4) gload16(Bs[QN][1] + (KO), Bdst + ((BUF) * 2 + (QN)) * BSZ + 4096); \
  } while (0)
#define RDA(BUF, Q) do { \
    const _Float16* p_ = Al + ((BUF) * 2 + (Q)) * ASZ + awoff; \
    _Pragma("unroll") \
    for (int f_ = 0; f_ < MF / 2; ++f_) { \
      ar[f_][0] = *(const h8*)(p_ + f_ * 1024 + s0); \
      ar[f_][1] = *(const h8*)(p_ + f_ * 1024 + s1); } \
  } while (0)
#define RDB(BUF, QN, D) do { \
    const _Float16* p_ = Bl + ((BUF) * 2 + (QN)) * BSZ + bwoff; \
    _Pragma("unroll") \
    for (int g_ = 0; g_ < NF / 2; ++g_) { \
      br[D][g_][0] = *(const h8*)(p_ + g_ * 1024 + s0); \
      br[D][g_][1] = *(const h8*)(p_ + g_ * 1024 + s1); } \
  } while (0)
#define MM(MH, D) do { \
    __builtin_amdgcn_s_setprio(1); \
    _Pragma("unroll") \
    for (int f_ = 0; f_ < MF / 2; ++f_) \
      _Pragma("unroll") \
      for (int g_ = 0; g_ < NF / 2; ++g_) { \
        acc[(MH) * (MF / 2) + f_][(D) * (NF / 2) + g_] = \
            mfma16(ar[f_][0], br[D][g_][0], acc[(MH) * (MF / 2) + f_][(D) * (NF / 2) + g_]); \
        acc[(MH) * (MF / 2) + f_][(D) * (NF / 2) + g_] = \
            mfma16(ar[f_][1], br[D][g_][1], acc[(MH) * (MF / 2) + f_][(D) * (NF / 2) + g_]); } \
    __builtin_amdgcn_s_setprio(0); \
    __builtin_amdgcn_sched_barrier(0); \
  } while (0)

  // prologue: tiles 0 (buf0) and 1 (buf1), region order Aq0,Bq0 | Bq1 | Aq1
  STA(0, 0, 0);  STB(0, 0, 0);  STB(0, 1, 0);  STA(0, 1, 0);
  STA(1, 0, 64); STB(1, 0, 64); STB(1, 1, 64); STA(1, 1, 64);

  int kof = 128;                         // element offset of tile 2it+2
  #pragma unroll 1
  for (int it = 0; it < 7; ++it) {       // NT/2 - 1 steady iterations
    VMW(V1); BARR; RDA(0, 0); RDB(0, 0, 0); LGKM0; MM(0, 0);
    VMW(V2); BARR; RDB(0, 1, 1); STA(0, 0, kof); STB(0, 0, kof); LGKM0; MM(0, 1);
    VMW(V1); BARR; RDA(0, 1); STB(0, 1, kof); LGKM0; MM(1, 1);
    BARR; STA(0, 1, kof); MM(1, 0);
    VMW(V1); BARR; RDA(1, 0); RDB(1, 0, 0); LGKM0; MM(0, 0);
    VMW(V2); BARR; RDB(1, 1, 1); STA(1, 0, kof + 64); STB(1, 0, kof + 64); LGKM0; MM(0, 1);
    VMW(V1); BARR; RDA(1, 1); STB(1, 1, kof + 64); LGKM0; MM(1, 1);
    BARR; STA(1, 1, kof + 64); MM(1, 0);
    kof += 128;
  }
  // last iteration: no staging, drain counts
  VMW(V1);  BARR; RDA(0, 0); RDB(0, 0, 0); LGKM0; MM(0, 0);
  VMW(V2);  BARR; RDB(0, 1, 1); LGKM0; MM(0, 1);
  VMW(VL3); BARR; RDA(0, 1); LGKM0; MM(1, 1);
  BARR; MM(1, 0);
  VMW(VL5); BARR; RDA(1, 0); RDB(1, 0, 0); LGKM0; MM(0, 0);
  VMW(VL6); BARR; RDB(1, 1, 1); LGKM0; MM(0, 1);
  VMW(0);   BARR; RDA(1, 1); LGKM0; MM(1, 1);
  BARR; MM(1, 0);

#undef VMW
#undef BARR
#undef LGKM0
#undef STA
#undef STB
#undef RDA
#undef RDB
#undef MM

  // ---- epilogue ----
  if (MODE == 0) {
    #pragma unroll
    for (int mi = 0; mi < MF; ++mi)
      #pragma unroll
      for (int nf = 0; nf < NF; ++nf)
        #pragma unroll
        for (int j = 0; j < 4; ++j) {
          int row = m0 + wm * (MF * 16) + mi * 16 + hi * 4 + j;
          int col = n0 + wn * (NF * 16) + nf * 16 + lo;
          C[(size_t)row * N + col] = acc[mi][nf][j];
        }
  } else {
    int which = n0 >> 10;                     // block-uniform (1024 % BN == 0)
    int cb0 = (n0 & 1023) + wn * (NF * 16);
    if (which == 2) {                         // V: transposed, j-contiguous h4
      #pragma unroll
      for (int mi = 0; mi < MF; ++mi) {
        int row0 = m0 + wm * (MF * 16) + mi * 16 + hi * 4;
        int bb = row0 >> 11, ss0 = row0 & 2047;
        #pragma unroll
        for (int nf = 0; nf < NF; ++nf) {
          int col = cb0 + nf * 16 + lo;
          int hh = col >> 6, hd = col & 63;
          h4 o4;
          o4[0] = (_Float16)acc[mi][nf][0]; o4[1] = (_Float16)acc[mi][nf][1];
          o4[2] = (_Float16)acc[mi][nf][2]; o4[3] = (_Float16)acc[mi][nf][3];
          *(h4*)(Vo + (size_t)(bb * 16 + hh) * 131072 + (size_t)hd * 2048 + ss0) = o4;
        }
      }
    } else {
      _Float16* Dst = (which == 0) ? Qo : Ko;
      float qs = (which == 0) ? 0.1803368801111137f : 1.0f;   // 1/8 * log2(e)
      #pragma unroll
      for (int mi = 0; mi < MF; ++mi)
        #pragma unroll
        for (int nf = 0; nf < NF; ++nf)
          #pragma unroll
          for (int j = 0; j < 4; ++j) {
            int row = m0 + wm * (MF * 16) + mi * 16 + hi * 4 + j;
            int col = cb0 + nf * 16 + lo;
            int hh = col >> 6, hd = col & 63;
            int bb = row >> 11, ss = row & 2047;
            Dst[(size_t)(bb * 16 + hh) * 131072 + (size_t)ss * 64 + hd] =
                (_Float16)(acc[mi][nf][j] * qs);
          }
    }
  }
}

// ---------------- causal flash attention, HD=64, S=2048 (R10 config) ---------
// grid 1024: bh = bid&63 (XCD = bh%8), qi = 15-(bid>>6) (longest first).
// Block = 8 waves x 16 q-rows = QBLK 128 (512 threads); KVBLK=64, dbuf.
// K rows sigma-PERMUTED in LDS (per-lane gload_lds source rows):
// sigma(r) = ((r&0x1C)<<1)|(r&3)|((r&32)>>3). Lane (hi,lo) reg j of QK^T
// frag kf holds S at global k = (kf&1)*32 + hi*8 + (kf>>1)*4 + j == its PV
// B-fragment slots -> P stays in-lane (cvt_pkrtz only, no cross-lane).
// voff == koff reindexed. Defer-max THR=8 (exp2 domain).
__global__ __launch_bounds__(512, 4) void attn_kernel(
    const _Float16* __restrict__ Q, const _Float16* __restrict__ Kb,
    const _Float16* __restrict__ Vb, _Float16* __restrict__ O)
{
  __shared__ _Float16 Kl[2 * 4096];   // [buf][sigma-row 64][chunk^row 8][8]
  __shared__ _Float16 Vl[2 * 4096];   // [buf][hd 64][chunk^row 8][8] (V^T)

  int bid = blockIdx.x;
  int bh = bid & 63, qi = 15 - (bid >> 6);
  int t = threadIdx.x, w = t >> 6, l = t & 63, lo = l & 15, hi = l >> 4;
  const size_t hoff = (size_t)bh * 131072;
  const _Float16* Kg = Kb + hoff;
  const _Float16* Vg = Vb + hoff;     // V^T: [64 hd][2048 s]
  int bb = bh >> 4, hh = bh & 15;

  // ---- staging: thread t covers LDS 16B-chunk t (1 K + 1 V gload) ----
  int rs = t >> 3, cs = t & 7;        // LDS row 0..63, chunk 0..7
  int sw_ = (cs ^ (rs & 7)) * 8;
  int sigma = ((rs & 0x1C) << 1) | (rs & 3) | ((rs & 32) >> 3);
  int srcK = sigma * 64 + sw_;
  int srcV = rs * 2048 + sw_;
  _Float16* kd0 = Kl + w * 512;       // wave-uniform dest base
  _Float16* vd0 = Vl + w * 512;

  // ---- fragment offsets: QK uses koff[kf][0/1], PV uses koff[df][ks] ----
  int koff[4][2];
  #pragma unroll
  for (int kf = 0; kf < 4; ++kf) {
    int row = kf * 16 + lo;
    koff[kf][0] = row * 64 + ((hi       ^ (row & 7)) * 8);
    koff[kf][1] = row * 64 + (((4 + hi) ^ (row & 7)) * 8);
  }

  h8 ones;
  #pragma unroll
  for (int e = 0; e < 8; ++e) ones[e] = (_Float16)1.0f;

  int qb = qi * 128 + w * 16;
  const _Float16* Qp = Q + hoff + (size_t)(qb + lo) * 64 + hi * 8;
  h8 qf0 = *(const h8*)(Qp);
  h8 qf1 = *(const h8*)(Qp + 32);

  f4 acc[4] = {};
  float m_run = -1e30f, l_run = 0.f;
  int nkt = 2 * qi + 2;

#define STAGE(buf, kt) do {                                                   \
    const _Float16* Kt_ = Kg + (size_t)(kt) * 4096;                           \
    const _Float16* Vt_ = Vg + (size_t)(kt) * 64;                             \
    gload16(Kt_ + srcK, kd0 + (buf) * 4096);                                  \
    gload16(Vt_ + srcV, vd0 + (buf) * 4096);                                  \
  } while (0)

#define ITER(kt, buf) do {                                                    \
    if ((kt) + 1 < nkt) STAGE(buf ^ 1, (kt) + 1);                             \
    const _Float16* Kc = Kl + (buf) * 4096;                                   \
    const _Float16* Vc = Vl + (buf) * 4096;                                   \
    f4 sc[4] = {};                                                            \
    __builtin_amdgcn_s_setprio(1);                                            \
    _Pragma("unroll")                                                         \
    for (int kf = 0; kf < 4; ++kf) {                                          \
      h8 k0 = *(const h8*)(Kc + koff[kf][0]);                                 \
      h8 k1 = *(const h8*)(Kc + koff[kf][1]);                                 \
      sc[kf] = mfma16(k0, qf0, sc[kf]);                                       \
      sc[kf] = mfma16(k1, qf1, sc[kf]);                                       \
    }                                                                         \
    __builtin_amdgcn_s_setprio(0);                                            \
    if ((kt) >= 2 * qi) {                                                     \
      int qg = qb + lo;                                                       \
      _Pragma("unroll")                                                       \
      for (int kf = 0; kf < 4; ++kf) {                                        \
        int kgb = (kt) * 64 + ((kf & 1) << 5) + ((kf >> 1) << 2) + hi * 8;    \
        _Pragma("unroll")                                                     \
        for (int j = 0; j < 4; ++j)                                           \
          if (kgb + j > qg) sc[kf][j] = -1e30f;                               \
      }                                                                       \
    }                                                                         \
    {                                                                         \
      f4 m4;                                                                  \
      _Pragma("unroll")                                                       \
      for (int c = 0; c < 4; ++c)                                             \
        m4[c] = fmaxf(max3f(sc[0][c], sc[1][c], sc[2][c]), sc[3][c]);         \
      float mx = fmaxf(max3f(m4[0], m4[1], m4[2]), m4[3]);                    \
      if (!__all(mx <= m_run + 8.f)) {        /* defer-max: rare path */      \
        mx = fmaxf(mx, __shfl_xor(mx, 16));                                   \
        mx = fmaxf(mx, __shfl_xor(mx, 32));                                   \
        float mn = fmaxf(m_run, mx);                                          \
        float cr = exp2f(m_run - mn);                                         \
        m_run = mn;                                                           \
        l_run *= cr;                                                          \
        _Pragma("unroll")                                                     \
        for (int df = 0; df < 4; ++df) {                                      \
          acc[df][0] *= cr; acc[df][1] *= cr;                                 \
          acc[df][2] *= cr; acc[df][3] *= cr;                                 \
        }                                                                     \
      }                                                                       \
    }                                                                         \
    f4 ls = {};                                                               \
    _Pragma("unroll")                                                         \
    for (int ks = 0; ks < 2; ++ks) {                                          \
      u4 tw;                                                                  \
      tw[0] = cvtpku(exp2f(sc[ks    ][0] - m_run),                            \
                     exp2f(sc[ks    ][1] - m_run));                           \
      tw[1] = cvtpku(exp2f(sc[ks    ][2] - m_run),                            \
                     exp2f(sc[ks    ][3] - m_run));                           \
      tw[2] = cvtpku(exp2f(sc[2 + ks][0] - m_run),                            \
                     exp2f(sc[2 + ks][1] - m_run));                           \
      tw[3] = cvtpku(exp2f(sc[2 + ks][2] - m_run),                            \
                     exp2f(sc[2 + ks][3] - m_run));                           \
      h8 pf = __builtin_bit_cast(h8, tw);                                     \
      ls = mfma16(ones, pf, ls);                                              \
      __builtin_amdgcn_s_setprio(1);                                          \
      _Pragma("unroll")                                                       \
      for (int df = 0; df < 4; ++df) {                                        \
        h8 vf = *(const h8*)(Vc + koff[df][ks]);                              \
        acc[df] = mfma16(vf, pf, acc[df]);                                    \
      }                                                                       \
      __builtin_amdgcn_s_setprio(0);                                          \
    }                                                                         \
    l_run += ls[0];                                                           \
    asm volatile("s_waitcnt vmcnt(0)" ::: "memory");                          \
    __syncthreads();                                                          \
  } while (0)

  STAGE(0, 0);
  asm volatile("s_waitcnt vmcnt(0)" ::: "memory");
  __syncthreads();

  for (int kt = 0; kt < nkt; kt += 2) {
    ITER(kt, 0);
    ITER(kt + 1, 1);
  }

  // epilogue: lane (hi,lo) holds O[q = qb+lo][d = df*16+hi*4+j]
  {
    float inv = 1.0f / l_run;
    int q = qb + lo;
    _Float16* Op = O + ((size_t)(bb * 2048 + q)) * 1024 + hh * 64 + (hi << 2);
    #pragma unroll
    for (int df = 0; df < 4; ++df) {
      h4 o4;
      o4[0] = (_Float16)(acc[df][0] * inv);
      o4[1] = (_Float16)(acc[df][1] * inv);
      o4[2] = (_Float16)(acc[df][2] * inv);
      o4[3] = (_Float16)(acc[df][3] * inv);
      *(h4*)(Op + df * 16) = o4;
    }
  }
#undef ITER
#undef STAGE
}

extern "C" void kernel_launch(void* const* d_in, const int* in_sizes, int n_in,
                              void* d_out, int out_size, void* d_ws, size_t ws_size,
                              hipStream_t stream)
{
  const float* x  = (const float*)d_in[0];
  const float* wq = (const float*)d_in[1];
  const float* wk = (const float*)d_in[2];
  const float* wv = (const float*)d_in[3];
  const float* wo = (const float*)d_in[4];
  // d_in[5] = causal mask: implemented analytically.

  char* ws = (char*)d_ws;
  _Float16* xb   = (_Float16*)(ws);                  // 16 MB, reused as Ob later
  _Float16* wqkv = (_Float16*)(ws + (16u << 20));    //  6 MB
  _Float16* wob  = (_Float16*)(ws + (22u << 20));    //  2 MB
  _Float16* Qb   = (_Float16*)(ws + (24u << 20));    // 16 MB
  _Float16* Kb   = (_Float16*)(ws + (40u << 20));    // 16 MB
  _Float16* Vb   = (_Float16*)(ws + (56u << 20));    // 16 MB (transposed)
  _Float16* Ob   = xb;                               // xb dead after QKV GEMM

  cvt_all<<<12288, 256, 0, stream>>>(x, wq, wk, wv, wo, xb, wqkv, wob);
  gemmT<1, 4, 2><<<64 * 24, 512, 0, stream>>>(xb, wqkv, nullptr, Qb, Kb, Vb, 3072, 24);
  attn_kernel<<<1024, 512, 0, stream>>>(Qb, Kb, Vb, Ob);
  gemmT<0, 4, 2><<<64 * 8, 512, 0, stream>>>(Ob, wob, (float*)d_out,
                                             nullptr, nullptr, nullptr, 1024, 8);
}